// Round 13
// baseline (45.555 us; speedup 1.0000x reference)
//
#include <hip/hip_runtime.h>

#define QDIM 21
#define NDIM 1368
#define OUTSTRIDE 64000
#define XTOT (64 * QDIM * NDIM)   // 1,838,592 x elements

typedef __attribute__((ext_vector_type(4))) float f32x4;
typedef __attribute__((ext_vector_type(8))) short bf16x8s;
typedef __attribute__((ext_vector_type(4))) unsigned int u32x4;

typedef __attribute__((address_space(1))) const unsigned int* gas_p;
typedef __attribute__((address_space(3))) unsigned int* las_p;

static __device__ __forceinline__ void gload16(const void* g, char* l) {
    __builtin_amdgcn_global_load_lds((gas_p)g, (las_p)(void*)l, 16, 0, 0);
}

// pack two f32 -> bf16x2 (round-half-up)
static __device__ __forceinline__ unsigned int pk2(float lo, float hi) {
    unsigned int a = __float_as_uint(lo) + 0x8000u;
    unsigned int b = __float_as_uint(hi) + 0x8000u;
    return __builtin_amdgcn_perm(b, a, 0x07060302);
}

static __device__ __forceinline__ bf16x8s pack8(f32x4 lo, f32x4 hi) {
    u32x4 p;
    p[0] = pk2(lo[0], lo[1]);
    p[1] = pk2(lo[2], lo[3]);
    p[2] = pk2(hi[0], hi[1]);
    p[3] = pk2(hi[2], hi[3]);
    return __builtin_bit_cast(bf16x8s, p);
}

// m204 bijective chunk swizzle within one filterbank's block range (R8 champion).
static __device__ __forceinline__ int chunk_swz(int idx, int n) {
    int xcd = idx & 7;
    int i   = idx >> 3;
    int q = n >> 3, r = n & 7;
    int base = (xcd < r) ? xcd * (q + 1) : r * (q + 1) + (xcd - r) * q;
    return base + i;
}

// x f32 -> bf16 conversion (x is read ~27x by the GEMM; convert once).
__global__ __launch_bounds__(256)
void xcvt(const float* __restrict__ x, unsigned short* __restrict__ xb) {
    int i = (blockIdx.x * 256 + threadIdx.x) * 8;
    if (i >= XTOT) return;
    f32x4 lo = *(const f32x4*)(x + i);
    f32x4 hi = *(const f32x4*)(x + i + 4);
    *(u32x4*)(xb + i) = __builtin_bit_cast(u32x4, pack8(lo, hi));
}

// One 4-wave block computes C[0:64, n0:n0+64] for window position p.
// B (weights): f32 gload_lds stages, 8 KB, XOR-swizzled (R8-proven).
// A: if ABF16, staged as bf16 from pre-converted xb (4 KB stage, no pack,
//    direct bf16x8s fragment reads); requires K%32==0 and start%8==0
//    (true for fb1/fb2). Else f32 from x (8 KB stage, R8 path; fb0+fallback).
// Ring: ABF16 -> 3 stages x 12 KB (counted vmcnt(3), stage t+2 after MFMA).
//       else  -> 2 stages x 16 KB (vmcnt(0); stage t+1 right after barrier).
template<int WLOG2, int NTX, int D, int P, int S, int K, bool ABF16>
__device__ __forceinline__ void fbk_body(const float* __restrict__ x,
                                         const unsigned short* __restrict__ xb,
                                         const float* __restrict__ W,
                                         float* __restrict__ out, int bid,
                                         char* ldsraw) {
    constexpr int WWIN = 1 << WLOG2;
    constexpr int G = (K + 31) / 32;          // 42 / 21 / 11
    constexpr bool TAIL = (K % 32) != 0;      // fb0 only (never with ABF16)
    constexpr int FMAXC = (K - 4) & ~3;
    constexpr int ASTB = ABF16 ? 4096 : 8192; // A stage bytes
    constexpr int STB  = ASTB + 8192;         // stage: 12288 / 16384
    constexpr int RING = ABF16 ? 3 : 2;

    const int n0 = (bid % NTX) * 64;
    const int p  = bid / NTX;
    const int start = (p == P - 1) ? (NDIM - WWIN) : p * S;

    const int tid  = threadIdx.x;
    const int wid  = tid >> 6;
    const int lane = tid & 63;
    const int wm = (wid >> 1) * 32;
    const int wn = (wid & 1) * 32;
    const int lr = lane & 15;
    const int hi = lane >> 4;
    const int kb = hi * 8;

    // ---- B staging constants (R8): wave stages rows 16wid..+15 via 2 gloads
    const int lrow = lane >> 3;
    const int g4   = ((lane & 7) ^ lrow) * 4;     // preswizzled source col (f32)
    const float* Wp  = W + (size_t)(p * D + n0) * K;
    const float* wb0 = Wp + (size_t)(16 * wid + lrow) * K;
    const float* wb1 = wb0 + (size_t)8 * K;
    const int wB = 2048 * wid;

    // ---- A staging constants
    const unsigned short* xbrow = nullptr;        // bf16 path: 1 gload/wave
    if constexpr (ABF16)
        xbrow = xb + (size_t)(16 * wid + (lane >> 2)) * (QDIM * NDIM) + start;
    const float* xb0f = x + (size_t)(16 * wid + lrow) * (QDIM * NDIM) + start;
    const int wA = ABF16 ? (1024 * wid) : (2048 * wid);

    auto STAGE = [&](int t, int sbase) {
        if constexpr (ABF16) {
            int f = t * 32 + (lane & 3) * 8;      // bf16 elems; no tail here
            int q = f >> WLOG2;
            int j = f & (WWIN - 1);
            gload16(xbrow + q * NDIM + j, ldsraw + sbase + wA);
        } else {
            int f = t * 32 + g4;
            if constexpr (TAIL) f = (f > FMAXC) ? FMAXC : f;
            int q = f >> WLOG2;
            int j = f & (WWIN - 1);
            const float* ga = xb0f + q * NDIM + j;
            char* la = ldsraw + sbase + wA;
            gload16(ga, la);
            gload16(ga + (size_t)8 * QDIM * NDIM, la + 1024);
        }
        int f = t * 32 + g4;
        if constexpr (TAIL) f = (f > FMAXC) ? FMAXC : f;
        char* lb = ldsraw + sbase + ASTB + wB;
        gload16(wb0 + f, lb);
        gload16(wb1 + f, lb + 1024);
    };

    // ---- fragment-read constants
    const int x7 = lr & 7;
    const int c0 = ((hi * 2)     ^ x7) * 16;
    const int c1 = ((hi * 2 + 1) ^ x7) * 16;
    const int oA0b = (wm + lr) * 64 + hi * 16;    // bf16 A (row*64 + hi*16)
    const int oA1b = oA0b + 1024;                 // +16 rows
    const int oA0 = (wm + lr) * 128;              // f32 A (R8)
    const int oA1 = (wm + 16 + lr) * 128;
    const int oB0 = ASTB + (wn + lr) * 128;
    const int oB1 = ASTB + (wn + 16 + lr) * 128;

    f32x4 acc[2][2] = {};

    STAGE(0, 0);
    if constexpr (RING == 3) STAGE(1, STB);

    int cs = 0;
    #pragma unroll 1
    for (int t = 0; t < G; ++t) {
        if constexpr (RING == 3) {
            if (t + 1 < G) { asm volatile("s_waitcnt vmcnt(3)" ::: "memory"); }
            else           { asm volatile("s_waitcnt vmcnt(0)" ::: "memory"); }
        } else {
            asm volatile("s_waitcnt vmcnt(0)" ::: "memory");
        }
        __builtin_amdgcn_sched_barrier(0);
        __builtin_amdgcn_s_barrier();
        __builtin_amdgcn_sched_barrier(0);

        if constexpr (RING == 2) {
            if (t + 1 < G) STAGE(t + 1, cs ^ STB);   // into buf read at t-1
            __builtin_amdgcn_sched_barrier(0);
        }

        const char* sb = ldsraw + cs;
        bf16x8s A0, A1;
        if constexpr (ABF16) {
            A0 = *(const bf16x8s*)(sb + oA0b);
            A1 = *(const bf16x8s*)(sb + oA1b);
        } else {
            f32x4 a00 = *(const f32x4*)(sb + oA0 + c0);
            f32x4 a01 = *(const f32x4*)(sb + oA0 + c1);
            f32x4 a10 = *(const f32x4*)(sb + oA1 + c0);
            f32x4 a11 = *(const f32x4*)(sb + oA1 + c1);
            if constexpr (TAIL) {
                if (t == G - 1 && kb >= (K & 31)) {
                    f32x4 z = {0.f, 0.f, 0.f, 0.f};
                    a00 = z; a01 = z; a10 = z; a11 = z;
                }
            }
            A0 = pack8(a00, a01);
            A1 = pack8(a10, a11);
        }
        f32x4 b00 = *(const f32x4*)(sb + oB0 + c0);
        f32x4 b01 = *(const f32x4*)(sb + oB0 + c1);
        f32x4 b10 = *(const f32x4*)(sb + oB1 + c0);
        f32x4 b11 = *(const f32x4*)(sb + oB1 + c1);
        bf16x8s B0 = pack8(b00, b01);
        bf16x8s B1 = pack8(b10, b11);

        acc[0][0] = __builtin_amdgcn_mfma_f32_16x16x32_bf16(A0, B0, acc[0][0], 0, 0, 0);
        acc[0][1] = __builtin_amdgcn_mfma_f32_16x16x32_bf16(A0, B1, acc[0][1], 0, 0, 0);
        acc[1][0] = __builtin_amdgcn_mfma_f32_16x16x32_bf16(A1, B0, acc[1][0], 0, 0, 0);
        acc[1][1] = __builtin_amdgcn_mfma_f32_16x16x32_bf16(A1, B1, acc[1][1], 0, 0, 0);

        __builtin_amdgcn_sched_barrier(0);
        if constexpr (RING == 3) {
            if (t + 2 < G) {
                int pb = (cs == 0) ? 2 * STB : cs - STB;  // slot (t-1)%3
                STAGE(t + 2, pb);
            }
            cs = (cs == 2 * STB) ? 0 : cs + STB;
        } else {
            cs ^= STB;
        }
    }

    // epilogue: C/D layout col = lane&15, row = (lane>>4)*4 + r
    const int colbase = p * D + n0;
    #pragma unroll
    for (int mi = 0; mi < 2; ++mi) {
        #pragma unroll
        for (int ni = 0; ni < 2; ++ni) {
            int col = colbase + wn + ni * 16 + lr;
            int rbase = wm + mi * 16 + hi * 4;
            #pragma unroll
            for (int r = 0; r < 4; ++r) {
                out[(size_t)(rbase + r) * OUTSTRIDE + col] = acc[mi][ni][r];
            }
        }
    }
}

// 1000 blocks, fb2 first (tail packing), R8 per-segment chunk swizzle.
// BF=true: fb2/fb1 use bf16-A (3-stage 12KB ring); fb0 keeps f32-A (2-stage).
// BF=false: all f32-A (fallback when ws too small). LDS 36864 -> 4 blocks/CU.
template<bool BF>
__global__ __launch_bounds__(256, 4)
void fbk_fused(const float* __restrict__ x,  const unsigned short* __restrict__ xb,
               const float* __restrict__ w0, const float* __restrict__ w1,
               const float* __restrict__ w2, float* __restrict__ out) {
    __shared__ __align__(16) char ldsraw[36864];
    const int pb = blockIdx.x;
    if (pb < 328) {
        // fb2: w=64, s=16, d=256, P=82, K=1344, 4 n-tiles
        fbk_body<6, 4, 256, 82, 16, 1344, BF>(x, xb, w2, out + 43008, chunk_swz(pb, 328), ldsraw);
    } else if (pb < 662) {
        // fb1: w=32, s=8, d=128, P=167, K=672, 2 n-tiles
        fbk_body<5, 2, 128, 167, 8, 672, BF>(x, xb, w1, out + 21632, chunk_swz(pb - 328, 334), ldsraw);
    } else {
        // fb0: w=16, s=4, d=64, P=338, K=336, 1 n-tile (S=4 -> misaligned bf16; f32 path)
        fbk_body<4, 1, 64, 338, 4, 336, false>(x, xb, w0, out, chunk_swz(pb - 662, 338), ldsraw);
    }
}

extern "C" void kernel_launch(void* const* d_in, const int* in_sizes, int n_in,
                              void* d_out, int out_size, void* d_ws, size_t ws_size,
                              hipStream_t stream) {
    const float* x  = (const float*)d_in[0];
    const float* w0 = (const float*)d_in[1];
    const float* w1 = (const float*)d_in[2];
    const float* w2 = (const float*)d_in[3];
    float* out = (float*)d_out;
    constexpr size_t XBF_BYTES = (size_t)XTOT * 2;   // 3.68 MB
    if (ws_size >= XBF_BYTES) {
        unsigned short* xbuf = (unsigned short*)d_ws;
        xcvt<<<dim3((XTOT / 8 + 255) / 256), 256, 0, stream>>>(x, xbuf);
        fbk_fused<true><<<dim3(1000), 256, 0, stream>>>(x, xbuf, w0, w1, w2, out);
    } else {
        fbk_fused<false><<<dim3(1000), 256, 0, stream>>>(x, nullptr, w0, w1, w2, out);
    }
}